// Round 5
// baseline (75.443 us; speedup 1.0000x reference)
//
#include <hip/hip_runtime.h>
#include <hip/hip_bf16.h>
#include <math.h>

#define DD 128
#define HH 64
#define TT 12

typedef __bf16 bf16x8 __attribute__((ext_vector_type(8)));
typedef float  f32x4  __attribute__((ext_vector_type(4)));

__device__ __forceinline__ float fast_tanh(float x) {
    float ex = __expf(2.f * x);
    return (ex - 1.f) * __builtin_amdgcn_rcpf(ex + 1.f);
}

// ---------------- Setup (fused): segment boundaries + W1 bf16 fragment pack.
__global__ void kSetup(const int* __restrict__ bidx, int* __restrict__ segs,
                       const float* __restrict__ W1, __bf16* __restrict__ W1f,
                       int M, int B) {
    int m = blockIdx.x * 256 + threadIdx.x;
    if (m < 16 * 512) {
        int f = m >> 9, l = (m >> 3) & 63, e = m & 7;
        int d = 32 * (f >> 2) + 8 * (l >> 4) + e;
        int j = 16 * (f & 3) + (l & 15);
        W1f[m] = (__bf16)W1[d * HH + j];
    }
    if (m >= M) return;
    int cur = bidx[m];
    int prev = (m == 0) ? -1 : bidx[m - 1];
    for (int b = prev + 1; b <= cur; ++b) segs[b] = m;
    if (m == M - 1)
        for (int b = cur + 1; b <= B; ++b) segs[b] = M;
}

// ---------------- Kernel A: dense unique-row scores -> uexp[n] = exp(score),
// and emit a row-major bf16 copy of the feature table (free: we already
// converted every element for the MFMA A-fragments).
__global__ __launch_bounds__(256) void kUScore(
    const float* __restrict__ feat, const __bf16* __restrict__ W1f,
    const float* __restrict__ b1, const float* __restrict__ W2,
    const float* __restrict__ b2, float* __restrict__ uexp,
    __bf16* __restrict__ featb, int N)
{
    int wave = threadIdx.x >> 6;
    int l = threadIdx.x & 63;
    int m0 = (blockIdx.x * 4 + wave) * 16;
    if (m0 >= N) return;
    int r = l & 15, grp = l >> 4;
    int row = min(m0 + r, N - 1);
    const float* xr = feat + (size_t)row * DD + grp * 8;

    bf16x8 a[4];
#pragma unroll
    for (int kk = 0; kk < 4; ++kk) {
        float4 u = *reinterpret_cast<const float4*>(xr + kk * 32);
        float4 v = *reinterpret_cast<const float4*>(xr + kk * 32 + 4);
        bf16x8 t;
        t[0] = (__bf16)u.x; t[1] = (__bf16)u.y; t[2] = (__bf16)u.z; t[3] = (__bf16)u.w;
        t[4] = (__bf16)v.x; t[5] = (__bf16)v.y; t[6] = (__bf16)v.z; t[7] = (__bf16)v.w;
        a[kk] = t;
    }
    // bf16 table copy (16B stores; clamped rows re-write identical data)
    __bf16* dst = featb + (size_t)row * DD + grp * 8;
#pragma unroll
    for (int kk = 0; kk < 4; ++kk)
        *reinterpret_cast<bf16x8*>(dst + kk * 32) = a[kk];

    f32x4 acc[4] = {};
#pragma unroll
    for (int kk = 0; kk < 4; ++kk) {
#pragma unroll
        for (int g = 0; g < 4; ++g) {
            bf16x8 bfr = *reinterpret_cast<const bf16x8*>(W1f + (kk * 4 + g) * 512 + l * 8);
            acc[g] = __builtin_amdgcn_mfma_f32_16x16x32_bf16(a[kk], bfr, acc[g], 0, 0, 0);
        }
    }

    float part[4] = {0.f, 0.f, 0.f, 0.f};
#pragma unroll
    for (int g = 0; g < 4; ++g) {
        int j = 16 * g + r;
        float b1j = b1[j], w2j = W2[j];
#pragma unroll
        for (int q = 0; q < 4; ++q)
            part[q] = fmaf(fast_tanh(acc[g][q] + b1j), w2j, part[q]);
    }
#pragma unroll
    for (int q = 0; q < 4; ++q) {
#pragma unroll
        for (int off = 1; off < 16; off <<= 1)
            part[q] += __shfl_xor(part[q], off, 64);
    }
    if (r == 0) {
        float b2v = b2[0];
#pragma unroll
        for (int q = 0; q < 4; ++q) {
            int mm = m0 + grp * 4 + q;
            if (mm < N) uexp[mm] = __expf(part[q] + b2v);  // scores bounded; max-sub dropped
        }
    }
}

// ---------------- Kernel B: wave-per-segment weighted pooling over bf16 rows.
// 64 lanes x bf16x2 = one full 256B row per load instruction. fidx/uexp for up
// to 64 pairs live in lanes; per-row broadcast via __shfl. No LDS, no syncs.
__global__ __launch_bounds__(256) void kPool(
    const __bf16* __restrict__ featb, const int* __restrict__ fidx,
    const float* __restrict__ uexp, const int* __restrict__ segs,
    float* __restrict__ pooled, int B)
{
    int w = threadIdx.x >> 6, lane = threadIdx.x & 63;
    int b = blockIdx.x * 4 + w;
    if (b >= B) return;
    int start = segs[b], end = segs[b + 1];

    float acc0 = 0.f, acc1 = 0.f, den = 0.f;
    for (int base = start; base < end; base += 64) {
        int t = base + lane;
        int fi = (t < end) ? fidx[t] : 0;
        float ue = (t < end) ? uexp[fi] : 0.f;
        int n = min(64, end - base);
#pragma unroll 4
        for (int r = 0; r < n; ++r) {
            int idx  = __shfl(fi, r, 64);
            float ev = __shfl(ue, r, 64);
            unsigned u = *reinterpret_cast<const unsigned*>(
                featb + (size_t)idx * DD + lane * 2);
            float lo = __builtin_bit_cast(float, u << 16);
            float hi = __builtin_bit_cast(float, u & 0xffff0000u);
            acc0 = fmaf(ev, lo, acc0);
            acc1 = fmaf(ev, hi, acc1);
            den += ev;
        }
    }
    float inv = 1.f / (den + 1e-16f);
    pooled[(size_t)b * DD + lane * 2]     = acc0 * inv;
    pooled[(size_t)b * DD + lane * 2 + 1] = acc1 * inv;
}

// ---------------- Kernel C: logits = relu(pooled@W3+b3)@W4 + b4
__global__ __launch_bounds__(128) void kPred(
    const float* __restrict__ pooled, const float* __restrict__ W3,
    const float* __restrict__ b3, const float* __restrict__ W4,
    const float* __restrict__ b4, float* __restrict__ out, int B)
{
    __shared__ float psh[16][DD];
    __shared__ float hsh[16][DD];
    int j = threadIdx.x;
    int b0 = blockIdx.x * 16;
#pragma unroll
    for (int mm = 0; mm < 16; ++mm) {
        int b = b0 + mm;
        psh[mm][j] = (b < B) ? pooled[(size_t)b * DD + j] : 0.f;
    }
    __syncthreads();
    float bj = b3[j];
    float h[16];
#pragma unroll
    for (int mm = 0; mm < 16; ++mm) h[mm] = bj;
    for (int d = 0; d < DD; d += 4) {
        float w0 = W3[(d + 0) * DD + j];
        float w1 = W3[(d + 1) * DD + j];
        float w2 = W3[(d + 2) * DD + j];
        float w3v = W3[(d + 3) * DD + j];
#pragma unroll
        for (int mm = 0; mm < 16; ++mm) {
            float4 pv = *reinterpret_cast<const float4*>(&psh[mm][d]);
            h[mm] = fmaf(pv.x, w0, h[mm]);
            h[mm] = fmaf(pv.y, w1, h[mm]);
            h[mm] = fmaf(pv.z, w2, h[mm]);
            h[mm] = fmaf(pv.w, w3v, h[mm]);
        }
    }
#pragma unroll
    for (int mm = 0; mm < 16; ++mm) hsh[mm][j] = fmaxf(h[mm], 0.f);
    __syncthreads();
    for (int p = j; p < 16 * TT; p += 128) {
        int mm = p / TT, t = p % TT;
        int b = b0 + mm;
        if (b < B) {
            float lg = b4[t];
            for (int d = 0; d < DD; ++d) lg = fmaf(hsh[mm][d], W4[d * TT + t], lg);
            out[(size_t)b * TT + t] = lg;
        }
    }
}

extern "C" void kernel_launch(void* const* d_in, const int* in_sizes, int n_in,
                              void* d_out, int out_size, void* d_ws, size_t ws_size,
                              hipStream_t stream) {
    const float* feat = (const float*)d_in[0];
    const int*   fidx = (const int*)d_in[1];
    const int*   bidx = (const int*)d_in[2];
    const float* W1 = (const float*)d_in[4];
    const float* b1 = (const float*)d_in[5];
    const float* W2 = (const float*)d_in[6];
    const float* b2 = (const float*)d_in[7];
    const float* W3 = (const float*)d_in[8];
    const float* b3 = (const float*)d_in[9];
    const float* W4 = (const float*)d_in[10];
    const float* b4 = (const float*)d_in[11];

    int N = in_sizes[0] / DD;      // unique substructure rows
    int M = in_sizes[1];
    int B = out_size / TT;
    float* out = (float*)d_out;

    float*  uexp   = (float*)d_ws;                          // N        (256 KB)
    float*  pooled = uexp + N;                              // B*DD     (4 MB)
    __bf16* W1f    = (__bf16*)(pooled + (size_t)B * DD);    // 16*512   (16 KB)
    __bf16* featb  = W1f + 16 * 512;                        // N*DD     (16 MB)
    int*    segs   = (int*)(featb + (size_t)N * DD);        // B+1

    kSetup<<<(M + 255) / 256, 256, 0, stream>>>(bidx, segs, W1, W1f, M, B);
    int tiles = (N + 15) / 16;
    kUScore<<<(tiles + 3) / 4, 256, 0, stream>>>(feat, W1f, b1, W2, b2, uexp, featb, N);
    kPool<<<(B + 3) / 4, 256, 0, stream>>>(featb, fidx, uexp, segs, pooled, B);
    kPred<<<(B + 15) / 16, 128, 0, stream>>>(pooled, W3, b3, W4, b4, out, B);
}

// Round 6
// 65.842 us; speedup vs baseline: 1.1458x; 1.1458x over previous
//
#include <hip/hip_runtime.h>
#include <hip/hip_bf16.h>
#include <math.h>

#define DD 128
#define HH 64
#define TT 12

typedef __bf16 bf16x8 __attribute__((ext_vector_type(8)));
typedef float  f32x4  __attribute__((ext_vector_type(4)));

__device__ __forceinline__ float fast_tanh(float x) {
    float ex = __expf(2.f * x);
    return (ex - 1.f) * __builtin_amdgcn_rcpf(ex + 1.f);
}

// ---------------- Setup (fused): segment boundaries + W1/W3 bf16 frag packs.
// W1f: 16 frags (f=kk*4+g):  elem(l,e) = W1[32kk+8*(l>>4)+e][16g+(l&15)]
// W3f: 32 frags (f=kk*8+g):  elem(l,e) = W3[32kk+8*(l>>4)+e][16g+(l&15)]
// Lane l reads frag as one bf16x8 at [f*512 + l*8].
__global__ void kSetup(const int* __restrict__ bidx, int* __restrict__ segs,
                       const float* __restrict__ W1, __bf16* __restrict__ W1f,
                       const float* __restrict__ W3, __bf16* __restrict__ W3f,
                       int M, int B) {
    int m = blockIdx.x * 256 + threadIdx.x;
    if (m < 16 * 512) {
        int f = m >> 9, l = (m >> 3) & 63, e = m & 7;
        int d = 32 * (f >> 2) + 8 * (l >> 4) + e;
        int j = 16 * (f & 3) + (l & 15);
        W1f[m] = (__bf16)W1[d * HH + j];
    } else if (m < 16 * 512 + 32 * 512) {
        int t = m - 16 * 512;
        int f = t >> 9, l = (t >> 3) & 63, e = t & 7;
        int d = 32 * (f >> 3) + 8 * (l >> 4) + e;
        int j = 16 * (f & 7) + (l & 15);
        W3f[t] = (__bf16)W3[d * DD + j];
    }
    if (m >= M) return;
    int cur = bidx[m];
    int prev = (m == 0) ? -1 : bidx[m - 1];
    for (int b = prev + 1; b <= cur; ++b) segs[b] = m;
    if (m == M - 1)
        for (int b = cur + 1; b <= B; ++b) segs[b] = M;
}

// ---------------- Kernel A: dense unique-row scores -> uexp[n] = exp(score),
// plus row-major bf16 table copy (conversion already needed for MFMA A-frags).
__global__ __launch_bounds__(256) void kUScore(
    const float* __restrict__ feat, const __bf16* __restrict__ W1f,
    const float* __restrict__ b1, const float* __restrict__ W2,
    const float* __restrict__ b2, float* __restrict__ uexp,
    __bf16* __restrict__ featb, int N)
{
    int wave = threadIdx.x >> 6;
    int l = threadIdx.x & 63;
    int m0 = (blockIdx.x * 4 + wave) * 16;
    if (m0 >= N) return;
    int r = l & 15, grp = l >> 4;
    int row = min(m0 + r, N - 1);
    const float* xr = feat + (size_t)row * DD + grp * 8;

    bf16x8 a[4];
#pragma unroll
    for (int kk = 0; kk < 4; ++kk) {
        float4 u = *reinterpret_cast<const float4*>(xr + kk * 32);
        float4 v = *reinterpret_cast<const float4*>(xr + kk * 32 + 4);
        bf16x8 t;
        t[0] = (__bf16)u.x; t[1] = (__bf16)u.y; t[2] = (__bf16)u.z; t[3] = (__bf16)u.w;
        t[4] = (__bf16)v.x; t[5] = (__bf16)v.y; t[6] = (__bf16)v.z; t[7] = (__bf16)v.w;
        a[kk] = t;
    }
    __bf16* dst = featb + (size_t)row * DD + grp * 8;
#pragma unroll
    for (int kk = 0; kk < 4; ++kk)
        *reinterpret_cast<bf16x8*>(dst + kk * 32) = a[kk];

    f32x4 acc[4] = {};
#pragma unroll
    for (int kk = 0; kk < 4; ++kk) {
#pragma unroll
        for (int g = 0; g < 4; ++g) {
            bf16x8 bfr = *reinterpret_cast<const bf16x8*>(W1f + (kk * 4 + g) * 512 + l * 8);
            acc[g] = __builtin_amdgcn_mfma_f32_16x16x32_bf16(a[kk], bfr, acc[g], 0, 0, 0);
        }
    }

    float part[4] = {0.f, 0.f, 0.f, 0.f};
#pragma unroll
    for (int g = 0; g < 4; ++g) {
        int j = 16 * g + r;
        float b1j = b1[j], w2j = W2[j];
#pragma unroll
        for (int q = 0; q < 4; ++q)
            part[q] = fmaf(fast_tanh(acc[g][q] + b1j), w2j, part[q]);
    }
#pragma unroll
    for (int q = 0; q < 4; ++q) {
#pragma unroll
        for (int off = 1; off < 16; off <<= 1)
            part[q] += __shfl_xor(part[q], off, 64);
    }
    if (r == 0) {
        float b2v = b2[0];
#pragma unroll
        for (int q = 0; q < 4; ++q) {
            int mm = m0 + grp * 4 + q;
            if (mm < N) uexp[mm] = __expf(part[q] + b2v);  // scores bounded; max-sub dropped
        }
    }
}

// ---------------- Kernel B: wave-per-segment weighted pooling over bf16 rows.
// 64 lanes x bf16x2 = one 256B row per load. Denominator via one butterfly
// per 64-chunk (not per row). Unroll 8 for deeper memory-level parallelism.
__global__ __launch_bounds__(256) void kPool(
    const __bf16* __restrict__ featb, const int* __restrict__ fidx,
    const float* __restrict__ uexp, const int* __restrict__ segs,
    float* __restrict__ pooled, int B)
{
    int w = threadIdx.x >> 6, lane = threadIdx.x & 63;
    int b = blockIdx.x * 4 + w;
    if (b >= B) return;
    int start = segs[b], end = segs[b + 1];
    const __bf16* fb = featb + lane * 2;

    float acc0 = 0.f, acc1 = 0.f, den = 0.f;
    for (int base = start; base < end; base += 64) {
        int t = base + lane;
        int fi = (t < end) ? fidx[t] : 0;
        float ue = (t < end) ? uexp[fi] : 0.f;
        // chunk denominator: full-wave butterfly sum of ue
        float ds = ue;
#pragma unroll
        for (int off = 1; off < 64; off <<= 1) ds += __shfl_xor(ds, off, 64);
        den += ds;
        int n = min(64, end - base);
#pragma unroll 8
        for (int r = 0; r < n; ++r) {
            int idx  = __shfl(fi, r, 64);
            float ev = __shfl(ue, r, 64);
            unsigned u = *reinterpret_cast<const unsigned*>(fb + (size_t)idx * DD);
            acc0 = fmaf(ev, __builtin_bit_cast(float, u << 16), acc0);
            acc1 = fmaf(ev, __builtin_bit_cast(float, u & 0xffff0000u), acc1);
        }
    }
    float inv = 1.f / (den + 1e-16f);
    pooled[(size_t)b * DD + lane * 2]     = acc0 * inv;
    pooled[(size_t)b * DD + lane * 2 + 1] = acc1 * inv;
}

// ---------------- Kernel C: logits = relu(pooled@W3+b3)@W4 + b4 via MFMA.
// 16 rows per wave (512 tiles, 128 blocks x 4 waves). W3f global bf16 frags
// (L2-hot, shared by all waves); W4/b3/b4 staged in LDS. Layer 2 in VALU +
// 4-step butterfly reduce over the 16 lanes sharing a row group.
__global__ __launch_bounds__(256) void kPred(
    const float* __restrict__ pooled, const __bf16* __restrict__ W3f,
    const float* __restrict__ b3, const float* __restrict__ W4,
    const float* __restrict__ b4, float* __restrict__ out, int B)
{
    __shared__ float sW4[DD][TT + 1];   // stride 13: 16 consecutive j -> distinct banks
    __shared__ float sb3[DD];
    __shared__ float sb4[TT];
    int tid = threadIdx.x;
    for (int i = tid; i < DD * TT; i += 256) sW4[i / TT][i % TT] = W4[i];
    if (tid < DD) sb3[tid] = b3[tid];
    if (tid < TT) sb4[tid] = b4[tid];
    __syncthreads();

    int wave = tid >> 6, l = tid & 63;
    int m0 = (blockIdx.x * 4 + wave) * 16;
    if (m0 >= B) return;                 // no barriers after this point
    int r = l & 15, grp = l >> 4;
    int row = min(m0 + r, B - 1);
    const float* pr = pooled + (size_t)row * DD + grp * 8;

    bf16x8 a[4];
#pragma unroll
    for (int kk = 0; kk < 4; ++kk) {
        float4 u = *reinterpret_cast<const float4*>(pr + kk * 32);
        float4 v = *reinterpret_cast<const float4*>(pr + kk * 32 + 4);
        bf16x8 t;
        t[0] = (__bf16)u.x; t[1] = (__bf16)u.y; t[2] = (__bf16)u.z; t[3] = (__bf16)u.w;
        t[4] = (__bf16)v.x; t[5] = (__bf16)v.y; t[6] = (__bf16)v.z; t[7] = (__bf16)v.w;
        a[kk] = t;
    }

    f32x4 acc[8] = {};
#pragma unroll
    for (int kk = 0; kk < 4; ++kk) {
#pragma unroll
        for (int g = 0; g < 8; ++g) {
            bf16x8 bfr = *reinterpret_cast<const bf16x8*>(W3f + (kk * 8 + g) * 512 + l * 8);
            acc[g] = __builtin_amdgcn_mfma_f32_16x16x32_bf16(a[kk], bfr, acc[g], 0, 0, 0);
        }
    }

    // layer 2: po[q][t] = sum over this lane's cols j=16g+r of relu(h)*W4[j][t]
    float po[4][TT];
#pragma unroll
    for (int q = 0; q < 4; ++q)
#pragma unroll
        for (int t = 0; t < TT; ++t) po[q][t] = 0.f;
#pragma unroll
    for (int g = 0; g < 8; ++g) {
        int j = 16 * g + r;
        float b3j = sb3[j];
        float h[4];
#pragma unroll
        for (int q = 0; q < 4; ++q) h[q] = fmaxf(acc[g][q] + b3j, 0.f);
#pragma unroll
        for (int t = 0; t < TT; ++t) {
            float wv = sW4[j][t];
#pragma unroll
            for (int q = 0; q < 4; ++q) po[q][t] = fmaf(h[q], wv, po[q][t]);
        }
    }
    // butterfly allreduce over the 16 lanes sharing a row group (xor bits 0..3)
#pragma unroll
    for (int off = 1; off < 16; off <<= 1)
#pragma unroll
        for (int q = 0; q < 4; ++q)
#pragma unroll
            for (int t = 0; t < TT; ++t) po[q][t] += __shfl_xor(po[q][t], off, 64);

    // lane r==t writes task t for its 4 rows (t compile-time: no dyn reg index)
#pragma unroll
    for (int t = 0; t < TT; ++t) {
        if (r == t) {
            float b4t = sb4[t];
#pragma unroll
            for (int q = 0; q < 4; ++q) {
                int ro = m0 + 4 * grp + q;
                if (ro < B) out[(size_t)ro * TT + t] = po[q][t] + b4t;
            }
        }
    }
}

extern "C" void kernel_launch(void* const* d_in, const int* in_sizes, int n_in,
                              void* d_out, int out_size, void* d_ws, size_t ws_size,
                              hipStream_t stream) {
    const float* feat = (const float*)d_in[0];
    const int*   fidx = (const int*)d_in[1];
    const int*   bidx = (const int*)d_in[2];
    const float* W1 = (const float*)d_in[4];
    const float* b1 = (const float*)d_in[5];
    const float* W2 = (const float*)d_in[6];
    const float* b2 = (const float*)d_in[7];
    const float* W3 = (const float*)d_in[8];
    const float* b3 = (const float*)d_in[9];
    const float* W4 = (const float*)d_in[10];
    const float* b4 = (const float*)d_in[11];

    int N = in_sizes[0] / DD;
    int M = in_sizes[1];
    int B = out_size / TT;
    float* out = (float*)d_out;

    float*  uexp   = (float*)d_ws;                          // N
    float*  pooled = uexp + N;                              // B*DD
    __bf16* W1f    = (__bf16*)(pooled + (size_t)B * DD);    // 8192
    __bf16* W3f    = W1f + 16 * 512;                        // 16384
    __bf16* featb  = W3f + 32 * 512;                        // N*DD
    int*    segs   = (int*)(featb + (size_t)N * DD);        // B+1

    kSetup<<<(M + 255) / 256, 256, 0, stream>>>(bidx, segs, W1, W1f, W3, W3f, M, B);
    int tiles = (N + 15) / 16;
    kUScore<<<(tiles + 3) / 4, 256, 0, stream>>>(feat, W1f, b1, W2, b2, uexp, featb, N);
    kPool<<<(B + 3) / 4, 256, 0, stream>>>(featb, fidx, uexp, segs, pooled, B);
    int ptiles = (B + 15) / 16;
    kPred<<<(ptiles + 3) / 4, 256, 0, stream>>>(pooled, W3f, b3, W4, b4, out, B);
}

// Round 7
// 53.922 us; speedup vs baseline: 1.3991x; 1.2210x over previous
//
#include <hip/hip_runtime.h>
#include <hip/hip_bf16.h>
#include <math.h>

#define DD 128
#define HH 64
#define TT 12

typedef __bf16 bf16x8 __attribute__((ext_vector_type(8)));
typedef float  f32x4  __attribute__((ext_vector_type(4)));

__device__ __forceinline__ float fast_tanh(float x) {
    float ex = __expf(2.f * x);
    return (ex - 1.f) * __builtin_amdgcn_rcpf(ex + 1.f);
}

// ---------------- K1: fused setup + dense unique-row scores.
// Setup blocks (0..nSetup-1): segs boundaries, W3f pack, uexp[N]=0, y zero row.
// Score blocks: pack W1 frags into LDS (coalesced src), MFMA scores,
// write uexp[n]=exp(score+b2) and weighted bf16 table y[n] = uexp[n]*x[n].
// B-frag layout (verified r2+): elem(lane l, e) = W[32kk+8*(l>>4)+e][16g+(l&15)]
__global__ __launch_bounds__(256) void kMain(
    const int* __restrict__ bidx, int* __restrict__ segs,
    const float* __restrict__ W1, const float* __restrict__ W3,
    __bf16* __restrict__ W3f, const float* __restrict__ feat,
    const float* __restrict__ b1, const float* __restrict__ W2,
    const float* __restrict__ b2, float* __restrict__ uexp,
    __bf16* __restrict__ ytab, int M, int B, int N, int nSetup)
{
    __shared__ __bf16 sW1f[16 * 512];
    int tid = threadIdx.x;
    if ((int)blockIdx.x < nSetup) {
        int m = blockIdx.x * 256 + tid;
        if (m < DD * DD) {  // W3f pack, source-major (coalesced read)
            int d = m >> 7, j = m & 127;
            int f = (d >> 5) * 8 + (j >> 4);
            int l = (((d >> 3) & 3) << 4) | (j & 15);
            W3f[f * 512 + l * 8 + (d & 7)] = (__bf16)W3[m];
        }
        if (blockIdx.x == 0) {
            if (tid >= 64 && tid < 128)
                reinterpret_cast<unsigned*>(ytab + (size_t)N * DD)[tid - 64] = 0u;
            if (tid == 0) uexp[N] = 0.f;
        }
        if (m < M) {
            int cur = bidx[m];
            int prev = (m == 0) ? -1 : bidx[m - 1];
            for (int b = prev + 1; b <= cur; ++b) segs[b] = m;
            if (m == M - 1)
                for (int b = cur + 1; b <= B; ++b) segs[b] = M;
        }
        return;
    }
    // ---- score path: W1 -> LDS frags, source-major (coalesced global read)
    for (int p = tid; p < HH * DD; p += 256) {
        int d = p >> 6, j = p & 63;
        int f = (d >> 5) * 4 + (j >> 4);
        int l = (((d >> 3) & 3) << 4) | (j & 15);
        sW1f[f * 512 + l * 8 + (d & 7)] = (__bf16)W1[p];
    }
    __syncthreads();
    int sb = blockIdx.x - nSetup;
    int wave = tid >> 6, l = tid & 63;
    int m0 = (sb * 4 + wave) * 16;
    if (m0 >= N) return;
    int r = l & 15, grp = l >> 4;
    int row = min(m0 + r, N - 1);
    const float* xr = feat + (size_t)row * DD + grp * 8;

    bf16x8 a[4];
#pragma unroll
    for (int kk = 0; kk < 4; ++kk) {
        float4 u = *reinterpret_cast<const float4*>(xr + kk * 32);
        float4 v = *reinterpret_cast<const float4*>(xr + kk * 32 + 4);
        bf16x8 t;
        t[0] = (__bf16)u.x; t[1] = (__bf16)u.y; t[2] = (__bf16)u.z; t[3] = (__bf16)u.w;
        t[4] = (__bf16)v.x; t[5] = (__bf16)v.y; t[6] = (__bf16)v.z; t[7] = (__bf16)v.w;
        a[kk] = t;
    }

    f32x4 acc[4] = {};
#pragma unroll
    for (int kk = 0; kk < 4; ++kk) {
#pragma unroll
        for (int g = 0; g < 4; ++g) {
            bf16x8 bfr = *reinterpret_cast<const bf16x8*>(sW1f + (kk * 4 + g) * 512 + l * 8);
            acc[g] = __builtin_amdgcn_mfma_f32_16x16x32_bf16(a[kk], bfr, acc[g], 0, 0, 0);
        }
    }

    // score[4grp+q] partials on (r = col j%16); reduce over r-bits
    float part[4] = {0.f, 0.f, 0.f, 0.f};
#pragma unroll
    for (int g = 0; g < 4; ++g) {
        int j = 16 * g + r;
        float b1j = b1[j], w2j = W2[j];
#pragma unroll
        for (int q = 0; q < 4; ++q)
            part[q] = fmaf(fast_tanh(acc[g][q] + b1j), w2j, part[q]);
    }
#pragma unroll
    for (int q = 0; q < 4; ++q) {
#pragma unroll
        for (int off = 1; off < 16; off <<= 1)
            part[q] += __shfl_xor(part[q], off, 64);
    }
    // transpose scores: this lane's A-row is m0+r; score[m0+r] lives at
    // lane src=16*(r>>2)+r, component r&3 (src's own r&3 == ours).
    float v01 = (r & 1) ? part[1] : part[0];
    float v23 = (r & 1) ? part[3] : part[2];
    float vsel = (r & 2) ? v23 : v01;
    float sc = __shfl(vsel, ((r >> 2) << 4) | r, 64);
    float ue = __expf(sc + b2[0]);        // scores bounded; max-sub dropped
    if (grp == 0) uexp[m0 + r] = ue;
    // weighted bf16 row: y = ue * x (product bf16-rounded; err ~0.4% per term)
    __bf16* dst = ytab + (size_t)row * DD + grp * 8;
#pragma unroll
    for (int kk = 0; kk < 4; ++kk) {
        bf16x8 t;
#pragma unroll
        for (int e = 0; e < 8; ++e) t[e] = (__bf16)(ue * (float)a[kk][e]);
        *reinterpret_cast<bf16x8*>(dst + kk * 32) = t;
    }
}

// ---------------- K2: pooling. 16 lanes/row (bf16x8/lane) -> 4 rows per load
// instruction; no per-row weight broadcast (rows pre-weighted); zero-row
// padding (idx=N) makes the inner loop fixed-shape for max loads in flight.
__global__ __launch_bounds__(256) void kPool(
    const __bf16* __restrict__ ytab, const int* __restrict__ fidx,
    const float* __restrict__ uexp, const int* __restrict__ segs,
    float* __restrict__ pooled, int B, int NZ)
{
    int w = threadIdx.x >> 6, lane = threadIdx.x & 63;
    int b = blockIdx.x * 4 + w;
    if (b >= B) return;
    int start = segs[b], end = segs[b + 1];
    int sub = lane >> 4, c16 = lane & 15;
    const __bf16* yb = ytab + c16 * 8;

    float acc[8] = {0.f, 0.f, 0.f, 0.f, 0.f, 0.f, 0.f, 0.f};
    float den = 0.f;
    for (int base = start; base < end; base += 64) {
        int t = base + lane;
        int fi = (t < end) ? fidx[t] : NZ;
        float ue = uexp[fi];              // uexp[NZ] = 0
        float ds = ue;
#pragma unroll
        for (int off = 1; off < 64; off <<= 1) ds += __shfl_xor(ds, off, 64);
        den += ds;
        int nit = (min(64, end - base) + 3) >> 2;
#pragma unroll 8
        for (int i = 0; i < nit; ++i) {
            int idx = __shfl(fi, 4 * i + sub, 64);   // my quad-row's index
            uint4 u4 = *reinterpret_cast<const uint4*>(yb + (size_t)idx * DD);
            acc[0] += __builtin_bit_cast(float, u4.x << 16);
            acc[1] += __builtin_bit_cast(float, u4.x & 0xffff0000u);
            acc[2] += __builtin_bit_cast(float, u4.y << 16);
            acc[3] += __builtin_bit_cast(float, u4.y & 0xffff0000u);
            acc[4] += __builtin_bit_cast(float, u4.z << 16);
            acc[5] += __builtin_bit_cast(float, u4.z & 0xffff0000u);
            acc[6] += __builtin_bit_cast(float, u4.w << 16);
            acc[7] += __builtin_bit_cast(float, u4.w & 0xffff0000u);
        }
    }
#pragma unroll
    for (int j = 0; j < 8; ++j) {
        acc[j] += __shfl_xor(acc[j], 16, 64);
        acc[j] += __shfl_xor(acc[j], 32, 64);
    }
    if (sub == 0) {
        float inv = 1.f / (den + 1e-16f);
        float* pb = pooled + (size_t)b * DD + c16 * 8;
        float4 o0 = make_float4(acc[0] * inv, acc[1] * inv, acc[2] * inv, acc[3] * inv);
        float4 o1 = make_float4(acc[4] * inv, acc[5] * inv, acc[6] * inv, acc[7] * inv);
        *reinterpret_cast<float4*>(pb) = o0;
        *reinterpret_cast<float4*>(pb + 4) = o1;
    }
}

// ---------------- K3: logits = relu(pooled@W3+b3)@W4 + b4 via MFMA (r6-proven)
__global__ __launch_bounds__(256) void kPred(
    const float* __restrict__ pooled, const __bf16* __restrict__ W3f,
    const float* __restrict__ b3, const float* __restrict__ W4,
    const float* __restrict__ b4, float* __restrict__ out, int B)
{
    __shared__ float sW4[DD][TT + 1];
    __shared__ float sb3[DD];
    __shared__ float sb4[TT];
    int tid = threadIdx.x;
    for (int i = tid; i < DD * TT; i += 256) sW4[i / TT][i % TT] = W4[i];
    if (tid < DD) sb3[tid] = b3[tid];
    if (tid < TT) sb4[tid] = b4[tid];
    __syncthreads();

    int wave = tid >> 6, l = tid & 63;
    int m0 = (blockIdx.x * 4 + wave) * 16;
    if (m0 >= B) return;
    int r = l & 15, grp = l >> 4;
    int row = min(m0 + r, B - 1);
    const float* pr = pooled + (size_t)row * DD + grp * 8;

    bf16x8 a[4];
#pragma unroll
    for (int kk = 0; kk < 4; ++kk) {
        float4 u = *reinterpret_cast<const float4*>(pr + kk * 32);
        float4 v = *reinterpret_cast<const float4*>(pr + kk * 32 + 4);
        bf16x8 t;
        t[0] = (__bf16)u.x; t[1] = (__bf16)u.y; t[2] = (__bf16)u.z; t[3] = (__bf16)u.w;
        t[4] = (__bf16)v.x; t[5] = (__bf16)v.y; t[6] = (__bf16)v.z; t[7] = (__bf16)v.w;
        a[kk] = t;
    }

    f32x4 acc[8] = {};
#pragma unroll
    for (int kk = 0; kk < 4; ++kk) {
#pragma unroll
        for (int g = 0; g < 8; ++g) {
            bf16x8 bfr = *reinterpret_cast<const bf16x8*>(W3f + (kk * 8 + g) * 512 + l * 8);
            acc[g] = __builtin_amdgcn_mfma_f32_16x16x32_bf16(a[kk], bfr, acc[g], 0, 0, 0);
        }
    }

    float po[4][TT];
#pragma unroll
    for (int q = 0; q < 4; ++q)
#pragma unroll
        for (int t = 0; t < TT; ++t) po[q][t] = 0.f;
#pragma unroll
    for (int g = 0; g < 8; ++g) {
        int j = 16 * g + r;
        float b3j = sb3[j];
        float h[4];
#pragma unroll
        for (int q = 0; q < 4; ++q) h[q] = fmaxf(acc[g][q] + b3j, 0.f);
#pragma unroll
        for (int t = 0; t < TT; ++t) {
            float wv = sW4[j][t];
#pragma unroll
            for (int q = 0; q < 4; ++q) po[q][t] = fmaf(h[q], wv, po[q][t]);
        }
    }
#pragma unroll
    for (int off = 1; off < 16; off <<= 1)
#pragma unroll
        for (int q = 0; q < 4; ++q)
#pragma unroll
            for (int t = 0; t < TT; ++t) po[q][t] += __shfl_xor(po[q][t], off, 64);

#pragma unroll
    for (int t = 0; t < TT; ++t) {
        if (r == t) {
            float b4t = sb4[t];
#pragma unroll
            for (int q = 0; q < 4; ++q) {
                int ro = m0 + 4 * grp + q;
                if (ro < B) out[(size_t)ro * TT + t] = po[q][t] + b4t;
            }
        }
    }
}

extern "C" void kernel_launch(void* const* d_in, const int* in_sizes, int n_in,
                              void* d_out, int out_size, void* d_ws, size_t ws_size,
                              hipStream_t stream) {
    const float* feat = (const float*)d_in[0];
    const int*   fidx = (const int*)d_in[1];
    const int*   bidx = (const int*)d_in[2];
    const float* W1 = (const float*)d_in[4];
    const float* b1 = (const float*)d_in[5];
    const float* W2 = (const float*)d_in[6];
    const float* b2 = (const float*)d_in[7];
    const float* W3 = (const float*)d_in[8];
    const float* b3 = (const float*)d_in[9];
    const float* W4 = (const float*)d_in[10];
    const float* b4 = (const float*)d_in[11];

    int N = in_sizes[0] / DD;
    int M = in_sizes[1];
    int B = out_size / TT;
    float* out = (float*)d_out;

    char* ws = (char*)d_ws;
    size_t o = 0;
    auto alloc = [&](size_t bytes) -> char* {
        char* p = ws + o;
        o = (o + bytes + 255) & ~(size_t)255;
        return p;
    };
    float*  pooled = (float*)alloc((size_t)B * DD * 4);
    float*  uexp   = (float*)alloc((size_t)(N + 1) * 4);
    __bf16* W3f    = (__bf16*)alloc(32 * 512 * 2);
    int*    segs   = (int*)alloc((size_t)(B + 1) * 4);
    __bf16* ytab   = (__bf16*)alloc((size_t)(N + 1) * DD * 2);

    int nSetup = (M + 255) / 256;
    int nScore = (N + 63) / 64;
    kMain<<<nSetup + nScore, 256, 0, stream>>>(bidx, segs, W1, W3, W3f, feat,
                                               b1, W2, b2, uexp, ytab, M, B, N, nSetup);
    kPool<<<(B + 3) / 4, 256, 0, stream>>>(ytab, fidx, uexp, segs, pooled, B, N);
    kPred<<<(((B + 15) / 16) + 3) / 4, 256, 0, stream>>>(pooled, W3f, b3, W4, b4, out, B);
}

// Round 8
// 52.321 us; speedup vs baseline: 1.4419x; 1.0306x over previous
//
#include <hip/hip_runtime.h>
#include <hip/hip_bf16.h>
#include <math.h>

#define DD 128
#define HH 64
#define TT 12

typedef __bf16 bf16x8 __attribute__((ext_vector_type(8)));
typedef float  f32x4  __attribute__((ext_vector_type(4)));

__device__ __forceinline__ float fast_tanh(float x) {
    float ex = __expf(2.f * x);
    return (ex - 1.f) * __builtin_amdgcn_rcpf(ex + 1.f);
}

// ---------------- K1: fused setup + dense unique-row scores.
// Setup blocks: segs boundaries, W3f pack, zero row/uexp pad.
// Score blocks: W1 frags in LDS, MFMA scores, uexp[n]=exp(score+b2),
// weighted bf16 table y[n] = uexp[n]*x[n].
__global__ __launch_bounds__(256) void kMain(
    const int* __restrict__ bidx, int* __restrict__ segs,
    const float* __restrict__ W1, const float* __restrict__ W3,
    __bf16* __restrict__ W3f, const float* __restrict__ feat,
    const float* __restrict__ b1, const float* __restrict__ W2,
    const float* __restrict__ b2, float* __restrict__ uexp,
    __bf16* __restrict__ ytab, int M, int B, int N, int nSetup)
{
    __shared__ __bf16 sW1f[16 * 512];
    int tid = threadIdx.x;
    if ((int)blockIdx.x < nSetup) {
        int m = blockIdx.x * 256 + tid;
        if (m < DD * DD) {  // W3f pack, source-major (coalesced read)
            int d = m >> 7, j = m & 127;
            int f = (d >> 5) * 8 + (j >> 4);
            int l = (((d >> 3) & 3) << 4) | (j & 15);
            W3f[f * 512 + l * 8 + (d & 7)] = (__bf16)W3[m];
        }
        if (blockIdx.x == 0) {
            if (tid >= 64 && tid < 128)
                reinterpret_cast<unsigned*>(ytab + (size_t)N * DD)[tid - 64] = 0u;
            if (tid == 0) uexp[N] = 0.f;
        }
        if (m < M) {
            int cur = bidx[m];
            int prev = (m == 0) ? -1 : bidx[m - 1];
            for (int b = prev + 1; b <= cur; ++b) segs[b] = m;
            if (m == M - 1)
                for (int b = cur + 1; b <= B; ++b) segs[b] = M;
        }
        return;
    }
    // ---- score path
    for (int p = tid; p < HH * DD; p += 256) {
        int d = p >> 6, j = p & 63;
        int f = (d >> 5) * 4 + (j >> 4);
        int l = (((d >> 3) & 3) << 4) | (j & 15);
        sW1f[f * 512 + l * 8 + (d & 7)] = (__bf16)W1[p];
    }
    __syncthreads();
    int sb = blockIdx.x - nSetup;
    int wave = tid >> 6, l = tid & 63;
    int m0 = (sb * 4 + wave) * 16;
    if (m0 >= N) return;
    int r = l & 15, grp = l >> 4;
    int row = min(m0 + r, N - 1);
    const float* xr = feat + (size_t)row * DD + grp * 8;

    bf16x8 a[4];
#pragma unroll
    for (int kk = 0; kk < 4; ++kk) {
        float4 u = *reinterpret_cast<const float4*>(xr + kk * 32);
        float4 v = *reinterpret_cast<const float4*>(xr + kk * 32 + 4);
        bf16x8 t;
        t[0] = (__bf16)u.x; t[1] = (__bf16)u.y; t[2] = (__bf16)u.z; t[3] = (__bf16)u.w;
        t[4] = (__bf16)v.x; t[5] = (__bf16)v.y; t[6] = (__bf16)v.z; t[7] = (__bf16)v.w;
        a[kk] = t;
    }

    f32x4 acc[4] = {};
#pragma unroll
    for (int kk = 0; kk < 4; ++kk) {
#pragma unroll
        for (int g = 0; g < 4; ++g) {
            bf16x8 bfr = *reinterpret_cast<const bf16x8*>(sW1f + (kk * 4 + g) * 512 + l * 8);
            acc[g] = __builtin_amdgcn_mfma_f32_16x16x32_bf16(a[kk], bfr, acc[g], 0, 0, 0);
        }
    }

    float part[4] = {0.f, 0.f, 0.f, 0.f};
#pragma unroll
    for (int g = 0; g < 4; ++g) {
        int j = 16 * g + r;
        float b1j = b1[j], w2j = W2[j];
#pragma unroll
        for (int q = 0; q < 4; ++q)
            part[q] = fmaf(fast_tanh(acc[g][q] + b1j), w2j, part[q]);
    }
#pragma unroll
    for (int q = 0; q < 4; ++q) {
#pragma unroll
        for (int off = 1; off < 16; off <<= 1)
            part[q] += __shfl_xor(part[q], off, 64);
    }
    // transpose scores: score[m0+r] lives at lane 16*(r>>2)+r, component r&3
    float v01 = (r & 1) ? part[1] : part[0];
    float v23 = (r & 1) ? part[3] : part[2];
    float vsel = (r & 2) ? v23 : v01;
    float sc = __shfl(vsel, ((r >> 2) << 4) | r, 64);
    float ue = __expf(sc + b2[0]);        // scores bounded; max-sub dropped
    if (grp == 0) uexp[m0 + r] = ue;
    __bf16* dst = ytab + (size_t)row * DD + grp * 8;
#pragma unroll
    for (int kk = 0; kk < 4; ++kk) {
        bf16x8 t;
#pragma unroll
        for (int e = 0; e < 8; ++e) t[e] = (__bf16)(ue * (float)a[kk][e]);
        *reinterpret_cast<bf16x8*>(dst + kk * 32) = t;
    }
}

// ---------------- K2: pooling. 16 lanes/row, 4 rows per load instruction.
// Row indices loaded DIRECTLY from fidx (4 distinct addrs per instr, one
// cache line, L1/L2-hot) — no bpermute in front of the row loads. Fixed
// 16-iteration chunk shape (zero-row padded) maximizes loads in flight.
__global__ __launch_bounds__(256) void kPool(
    const __bf16* __restrict__ ytab, const int* __restrict__ fidx,
    const float* __restrict__ uexp, const int* __restrict__ segs,
    float* __restrict__ pooled, int B, int NZ, int M)
{
    int w = threadIdx.x >> 6, lane = threadIdx.x & 63;
    int b = blockIdx.x * 4 + w;
    if (b >= B) return;
    int start = segs[b], end = segs[b + 1];
    int sub = lane >> 4, c16 = lane & 15;
    const __bf16* yb = ytab + c16 * 8;

    float acc[8] = {0.f, 0.f, 0.f, 0.f, 0.f, 0.f, 0.f, 0.f};
    float den = 0.f;
    for (int base = start; base < end; base += 64) {
        // row indices for my sub-slot: 16 independent broadcast loads
        int idxs[16];
#pragma unroll
        for (int i = 0; i < 16; ++i) {
            int p = base + 4 * i + sub;
            int v = fidx[min(p, M - 1)];
            idxs[i] = (p < end) ? v : NZ;          // NZ -> zero row
        }
        // denominator: coalesced fidx + uexp gather + butterfly
        int t = base + lane;
        int fi = (t < end) ? fidx[t] : NZ;
        float ue = uexp[fi];                        // uexp[NZ] = 0
        float ds = ue;
#pragma unroll
        for (int off = 1; off < 64; off <<= 1) ds += __shfl_xor(ds, off, 64);
        den += ds;
        // 16 row loads, fully pipelined (addresses all ready)
#pragma unroll
        for (int i = 0; i < 16; ++i) {
            uint4 u4 = *reinterpret_cast<const uint4*>(yb + (size_t)idxs[i] * DD);
            acc[0] += __builtin_bit_cast(float, u4.x << 16);
            acc[1] += __builtin_bit_cast(float, u4.x & 0xffff0000u);
            acc[2] += __builtin_bit_cast(float, u4.y << 16);
            acc[3] += __builtin_bit_cast(float, u4.y & 0xffff0000u);
            acc[4] += __builtin_bit_cast(float, u4.z << 16);
            acc[5] += __builtin_bit_cast(float, u4.z & 0xffff0000u);
            acc[6] += __builtin_bit_cast(float, u4.w << 16);
            acc[7] += __builtin_bit_cast(float, u4.w & 0xffff0000u);
        }
    }
#pragma unroll
    for (int j = 0; j < 8; ++j) {
        acc[j] += __shfl_xor(acc[j], 16, 64);
        acc[j] += __shfl_xor(acc[j], 32, 64);
    }
    if (sub == 0) {
        float inv = 1.f / (den + 1e-16f);
        float* pb = pooled + (size_t)b * DD + c16 * 8;
        float4 o0 = make_float4(acc[0] * inv, acc[1] * inv, acc[2] * inv, acc[3] * inv);
        float4 o1 = make_float4(acc[4] * inv, acc[5] * inv, acc[6] * inv, acc[7] * inv);
        *reinterpret_cast<float4*>(pb) = o0;
        *reinterpret_cast<float4*>(pb + 4) = o1;
    }
}

// ---------------- K3: logits = relu(pooled@W3+b3)@W4 + b4 via MFMA (r6-proven)
__global__ __launch_bounds__(256) void kPred(
    const float* __restrict__ pooled, const __bf16* __restrict__ W3f,
    const float* __restrict__ b3, const float* __restrict__ W4,
    const float* __restrict__ b4, float* __restrict__ out, int B)
{
    __shared__ float sW4[DD][TT + 1];
    __shared__ float sb3[DD];
    __shared__ float sb4[TT];
    int tid = threadIdx.x;
    for (int i = tid; i < DD * TT; i += 256) sW4[i / TT][i % TT] = W4[i];
    if (tid < DD) sb3[tid] = b3[tid];
    if (tid < TT) sb4[tid] = b4[tid];
    __syncthreads();

    int wave = tid >> 6, l = tid & 63;
    int m0 = (blockIdx.x * 4 + wave) * 16;
    if (m0 >= B) return;
    int r = l & 15, grp = l >> 4;
    int row = min(m0 + r, B - 1);
    const float* pr = pooled + (size_t)row * DD + grp * 8;

    bf16x8 a[4];
#pragma unroll
    for (int kk = 0; kk < 4; ++kk) {
        float4 u = *reinterpret_cast<const float4*>(pr + kk * 32);
        float4 v = *reinterpret_cast<const float4*>(pr + kk * 32 + 4);
        bf16x8 t;
        t[0] = (__bf16)u.x; t[1] = (__bf16)u.y; t[2] = (__bf16)u.z; t[3] = (__bf16)u.w;
        t[4] = (__bf16)v.x; t[5] = (__bf16)v.y; t[6] = (__bf16)v.z; t[7] = (__bf16)v.w;
        a[kk] = t;
    }

    f32x4 acc[8] = {};
#pragma unroll
    for (int kk = 0; kk < 4; ++kk) {
#pragma unroll
        for (int g = 0; g < 8; ++g) {
            bf16x8 bfr = *reinterpret_cast<const bf16x8*>(W3f + (kk * 8 + g) * 512 + l * 8);
            acc[g] = __builtin_amdgcn_mfma_f32_16x16x32_bf16(a[kk], bfr, acc[g], 0, 0, 0);
        }
    }

    float po[4][TT];
#pragma unroll
    for (int q = 0; q < 4; ++q)
#pragma unroll
        for (int t = 0; t < TT; ++t) po[q][t] = 0.f;
#pragma unroll
    for (int g = 0; g < 8; ++g) {
        int j = 16 * g + r;
        float b3j = sb3[j];
        float h[4];
#pragma unroll
        for (int q = 0; q < 4; ++q) h[q] = fmaxf(acc[g][q] + b3j, 0.f);
#pragma unroll
        for (int t = 0; t < TT; ++t) {
            float wv = sW4[j][t];
#pragma unroll
            for (int q = 0; q < 4; ++q) po[q][t] = fmaf(h[q], wv, po[q][t]);
        }
    }
#pragma unroll
    for (int off = 1; off < 16; off <<= 1)
#pragma unroll
        for (int q = 0; q < 4; ++q)
#pragma unroll
            for (int t = 0; t < TT; ++t) po[q][t] += __shfl_xor(po[q][t], off, 64);

#pragma unroll
    for (int t = 0; t < TT; ++t) {
        if (r == t) {
            float b4t = sb4[t];
#pragma unroll
            for (int q = 0; q < 4; ++q) {
                int ro = m0 + 4 * grp + q;
                if (ro < B) out[(size_t)ro * TT + t] = po[q][t] + b4t;
            }
        }
    }
}

extern "C" void kernel_launch(void* const* d_in, const int* in_sizes, int n_in,
                              void* d_out, int out_size, void* d_ws, size_t ws_size,
                              hipStream_t stream) {
    const float* feat = (const float*)d_in[0];
    const int*   fidx = (const int*)d_in[1];
    const int*   bidx = (const int*)d_in[2];
    const float* W1 = (const float*)d_in[4];
    const float* b1 = (const float*)d_in[5];
    const float* W2 = (const float*)d_in[6];
    const float* b2 = (const float*)d_in[7];
    const float* W3 = (const float*)d_in[8];
    const float* b3 = (const float*)d_in[9];
    const float* W4 = (const float*)d_in[10];
    const float* b4 = (const float*)d_in[11];

    int N = in_sizes[0] / DD;
    int M = in_sizes[1];
    int B = out_size / TT;
    float* out = (float*)d_out;

    char* ws = (char*)d_ws;
    size_t o = 0;
    auto alloc = [&](size_t bytes) -> char* {
        char* p = ws + o;
        o = (o + bytes + 255) & ~(size_t)255;
        return p;
    };
    float*  pooled = (float*)alloc((size_t)B * DD * 4);
    float*  uexp   = (float*)alloc((size_t)(N + 1) * 4);
    __bf16* W3f    = (__bf16*)alloc(32 * 512 * 2);
    int*    segs   = (int*)alloc((size_t)(B + 1) * 4);
    __bf16* ytab   = (__bf16*)alloc((size_t)(N + 1) * DD * 2);

    int nSetup = (M + 255) / 256;
    int nScore = (N + 63) / 64;
    kMain<<<nSetup + nScore, 256, 0, stream>>>(bidx, segs, W1, W3, W3f, feat,
                                               b1, W2, b2, uexp, ytab, M, B, N, nSetup);
    kPool<<<(B + 3) / 4, 256, 0, stream>>>(ytab, fidx, uexp, segs, pooled, B, N, M);
    kPred<<<(((B + 15) / 16) + 3) / 4, 256, 0, stream>>>(pooled, W3f, b3, W4, b4, out, B);
}

// Round 9
// 39.671 us; speedup vs baseline: 1.9017x; 1.3189x over previous
//
#include <hip/hip_runtime.h>
#include <hip/hip_bf16.h>
#include <math.h>

#define DD 128
#define HH 64
#define TT 12

typedef __bf16 bf16x8 __attribute__((ext_vector_type(8)));
typedef float  f32x4  __attribute__((ext_vector_type(4)));

__device__ __forceinline__ float fast_tanh(float x) {
    float ex = __expf(2.f * x);
    return (ex - 1.f) * __builtin_amdgcn_rcpf(ex + 1.f);
}

// ---------------- K1: fused setup + dense unique-row scores.
// Setup blocks: segs boundaries, W3f/W4f packs, zero row/uexp pad.
// Score blocks: W1 frags in LDS, MFMA scores, uexp[n]=exp(score+b2),
// weighted bf16 table y[n] = uexp[n]*x[n].
// B-frag layout: elem(lane l, e) = W[32kk + 8*(l>>4) + e][16g + (l&15)]
__global__ __launch_bounds__(256) void kMain(
    const int* __restrict__ bidx, int* __restrict__ segs,
    const float* __restrict__ W1, const float* __restrict__ W3,
    __bf16* __restrict__ W3f, const float* __restrict__ W4,
    __bf16* __restrict__ W4f, const float* __restrict__ feat,
    const float* __restrict__ b1, const float* __restrict__ W2,
    const float* __restrict__ b2, float* __restrict__ uexp,
    __bf16* __restrict__ ytab, int M, int B, int N, int nSetup)
{
    __shared__ __bf16 sW1f[16 * 512];
    int tid = threadIdx.x;
    if ((int)blockIdx.x < nSetup) {
        int m = blockIdx.x * 256 + tid;
        if (m < DD * DD) {  // W3f pack, source-major (coalesced read)
            int d = m >> 7, j = m & 127;
            int f = (d >> 5) * 8 + (j >> 4);
            int l = (((d >> 3) & 3) << 4) | (j & 15);
            W3f[f * 512 + l * 8 + (d & 7)] = (__bf16)W3[m];
        }
        if (blockIdx.x == 0) {
            // W4f: padded 128x16 B-frags (cols 12..15 = 0)
            for (int p = tid; p < 4 * 512; p += 256) {
                int f = p >> 9, l = (p >> 3) & 63, e = p & 7;
                int d = 32 * f + 8 * (l >> 4) + e;
                int c = l & 15;
                W4f[p] = (c < TT) ? (__bf16)W4[d * TT + c] : (__bf16)0.f;
            }
            if (tid >= 64 && tid < 128)
                reinterpret_cast<unsigned*>(ytab + (size_t)N * DD)[tid - 64] = 0u;
            if (tid == 0) uexp[N] = 0.f;
        }
        if (m < M) {
            int cur = bidx[m];
            int prev = (m == 0) ? -1 : bidx[m - 1];
            for (int b = prev + 1; b <= cur; ++b) segs[b] = m;
            if (m == M - 1)
                for (int b = cur + 1; b <= B; ++b) segs[b] = M;
        }
        return;
    }
    // ---- score path
    for (int p = tid; p < HH * DD; p += 256) {
        int d = p >> 6, j = p & 63;
        int f = (d >> 5) * 4 + (j >> 4);
        int l = (((d >> 3) & 3) << 4) | (j & 15);
        sW1f[f * 512 + l * 8 + (d & 7)] = (__bf16)W1[p];
    }
    __syncthreads();
    int sb = blockIdx.x - nSetup;
    int wave = tid >> 6, l = tid & 63;
    int m0 = (sb * 4 + wave) * 16;
    if (m0 >= N) return;
    int r = l & 15, grp = l >> 4;
    int row = min(m0 + r, N - 1);
    const float* xr = feat + (size_t)row * DD + grp * 8;

    bf16x8 a[4];
#pragma unroll
    for (int kk = 0; kk < 4; ++kk) {
        float4 u = *reinterpret_cast<const float4*>(xr + kk * 32);
        float4 v = *reinterpret_cast<const float4*>(xr + kk * 32 + 4);
        bf16x8 t;
        t[0] = (__bf16)u.x; t[1] = (__bf16)u.y; t[2] = (__bf16)u.z; t[3] = (__bf16)u.w;
        t[4] = (__bf16)v.x; t[5] = (__bf16)v.y; t[6] = (__bf16)v.z; t[7] = (__bf16)v.w;
        a[kk] = t;
    }

    f32x4 acc[4] = {};
#pragma unroll
    for (int kk = 0; kk < 4; ++kk) {
#pragma unroll
        for (int g = 0; g < 4; ++g) {
            bf16x8 bfr = *reinterpret_cast<const bf16x8*>(sW1f + (kk * 4 + g) * 512 + l * 8);
            acc[g] = __builtin_amdgcn_mfma_f32_16x16x32_bf16(a[kk], bfr, acc[g], 0, 0, 0);
        }
    }

    float part[4] = {0.f, 0.f, 0.f, 0.f};
#pragma unroll
    for (int g = 0; g < 4; ++g) {
        int j = 16 * g + r;
        float b1j = b1[j], w2j = W2[j];
#pragma unroll
        for (int q = 0; q < 4; ++q)
            part[q] = fmaf(fast_tanh(acc[g][q] + b1j), w2j, part[q]);
    }
#pragma unroll
    for (int q = 0; q < 4; ++q) {
#pragma unroll
        for (int off = 1; off < 16; off <<= 1)
            part[q] += __shfl_xor(part[q], off, 64);
    }
    // transpose scores: score[m0+r] lives at lane 16*(r>>2)+r, component r&3
    float v01 = (r & 1) ? part[1] : part[0];
    float v23 = (r & 1) ? part[3] : part[2];
    float vsel = (r & 2) ? v23 : v01;
    float sc = __shfl(vsel, ((r >> 2) << 4) | r, 64);
    float ue = __expf(sc + b2[0]);        // scores bounded; max-sub dropped
    if (grp == 0) uexp[m0 + r] = ue;
    __bf16* dst = ytab + (size_t)row * DD + grp * 8;
#pragma unroll
    for (int kk = 0; kk < 4; ++kk) {
        bf16x8 t;
#pragma unroll
        for (int e = 0; e < 8; ++e) t[e] = (__bf16)(ue * (float)a[kk][e]);
        *reinterpret_cast<bf16x8*>(dst + kk * 32) = t;
    }
}

// ---------------- K2: fused pooling + predictor, one block per 16-molecule
// tile. 8 waves x 2 segments each; pooled rows -> LDS as bf16 (exactly what
// the pred MFMA wants — same rounding kPred did from global). After barrier,
// wave 0 runs pred: W3-MFMA -> relu -> h to LDS bf16 -> W4-MFMA -> out.
__global__ __launch_bounds__(512) void kPoolPred(
    const __bf16* __restrict__ ytab, const int* __restrict__ fidx,
    const float* __restrict__ uexp, const int* __restrict__ segs,
    const __bf16* __restrict__ W3f, const __bf16* __restrict__ W4f,
    const float* __restrict__ b3, const float* __restrict__ b4,
    float* __restrict__ out, int B, int NZ, int M)
{
    __shared__ __bf16 psh[16][DD];   // pooled tile, bf16
    __shared__ __bf16 hsh[16][DD];   // relu hidden, bf16
    int tid = threadIdx.x;
    int w = tid >> 6, lane = tid & 63;
    int tile = blockIdx.x;
    int sub = lane >> 4, c16 = lane & 15;
    const __bf16* yb = ytab + c16 * 8;

#pragma unroll
    for (int s = 0; s < 2; ++s) {
        int seg = tile * 16 + 2 * w + s;
        int rowit = 2 * w + s;
        float acc[8] = {0.f, 0.f, 0.f, 0.f, 0.f, 0.f, 0.f, 0.f};
        float denl = 0.f;
        if (seg < B) {
            int start = segs[seg], end = segs[seg + 1];
            for (int base = start; base < end; base += 64) {
                int idxs[16];
#pragma unroll
                for (int i = 0; i < 16; ++i) {
                    int p = base + 4 * i + sub;
                    int v = fidx[min(p, M - 1)];
                    idxs[i] = (p < end) ? v : NZ;          // NZ -> zero row
                }
                int t = base + lane;
                int fi = (t < end) ? fidx[t] : NZ;
                denl += uexp[fi];                           // uexp[NZ] = 0
#pragma unroll
                for (int i = 0; i < 16; ++i) {
                    uint4 u4 = *reinterpret_cast<const uint4*>(yb + (size_t)idxs[i] * DD);
                    acc[0] += __builtin_bit_cast(float, u4.x << 16);
                    acc[1] += __builtin_bit_cast(float, u4.x & 0xffff0000u);
                    acc[2] += __builtin_bit_cast(float, u4.y << 16);
                    acc[3] += __builtin_bit_cast(float, u4.y & 0xffff0000u);
                    acc[4] += __builtin_bit_cast(float, u4.z << 16);
                    acc[5] += __builtin_bit_cast(float, u4.z & 0xffff0000u);
                    acc[6] += __builtin_bit_cast(float, u4.w << 16);
                    acc[7] += __builtin_bit_cast(float, u4.w & 0xffff0000u);
                }
            }
        }
        // denominator: butterfly over 64 lanes
        float den = denl;
#pragma unroll
        for (int off = 1; off < 64; off <<= 1) den += __shfl_xor(den, off, 64);
        // numerator: reduce across the 4 sub-groups
#pragma unroll
        for (int j = 0; j < 8; ++j) {
            acc[j] += __shfl_xor(acc[j], 16, 64);
            acc[j] += __shfl_xor(acc[j], 32, 64);
        }
        if (sub == 0) {
            float inv = 1.f / (den + 1e-16f);
            bf16x8 o;
#pragma unroll
            for (int j = 0; j < 8; ++j) o[j] = (__bf16)(acc[j] * inv);
            *reinterpret_cast<bf16x8*>(&psh[rowit][c16 * 8]) = o;
        }
    }
    __syncthreads();

    if (w != 0) return;
    // ---- pred phase (wave 0 only): logits = relu(P@W3+b3)@W4 + b4
    int r = lane & 15, grp = lane >> 4;
    bf16x8 a[4];
#pragma unroll
    for (int kk = 0; kk < 4; ++kk)
        a[kk] = *reinterpret_cast<const bf16x8*>(&psh[r][kk * 32 + grp * 8]);

    f32x4 acc[8] = {};
#pragma unroll
    for (int kk = 0; kk < 4; ++kk) {
#pragma unroll
        for (int g = 0; g < 8; ++g) {
            bf16x8 bfr = *reinterpret_cast<const bf16x8*>(W3f + (kk * 8 + g) * 512 + lane * 8);
            acc[g] = __builtin_amdgcn_mfma_f32_16x16x32_bf16(a[kk], bfr, acc[g], 0, 0, 0);
        }
    }
    // h = relu(acc + b3) -> LDS bf16 (transpose for next MFMA's A-frag)
#pragma unroll
    for (int g = 0; g < 8; ++g) {
        int j = 16 * g + r;
        float b3j = b3[j];
#pragma unroll
        for (int q = 0; q < 4; ++q)
            hsh[4 * grp + q][j] = (__bf16)fmaxf(acc[g][q] + b3j, 0.f);
    }
    // layer 2: [16x128]@[128x16] (cols 12..15 zero-padded)
    f32x4 acc2 = {};
#pragma unroll
    for (int kk = 0; kk < 4; ++kk) {
        bf16x8 ah = *reinterpret_cast<const bf16x8*>(&hsh[r][kk * 32 + grp * 8]);
        bf16x8 bw = *reinterpret_cast<const bf16x8*>(W4f + kk * 512 + lane * 8);
        acc2 = __builtin_amdgcn_mfma_f32_16x16x32_bf16(ah, bw, acc2, 0, 0, 0);
    }
    int t = r;                 // D col = task
    if (t < TT) {
        float b4t = b4[t];
#pragma unroll
        for (int q = 0; q < 4; ++q) {
            int ro = tile * 16 + 4 * grp + q;
            if (ro < B) out[(size_t)ro * TT + t] = acc2[q] + b4t;
        }
    }
}

extern "C" void kernel_launch(void* const* d_in, const int* in_sizes, int n_in,
                              void* d_out, int out_size, void* d_ws, size_t ws_size,
                              hipStream_t stream) {
    const float* feat = (const float*)d_in[0];
    const int*   fidx = (const int*)d_in[1];
    const int*   bidx = (const int*)d_in[2];
    const float* W1 = (const float*)d_in[4];
    const float* b1 = (const float*)d_in[5];
    const float* W2 = (const float*)d_in[6];
    const float* b2 = (const float*)d_in[7];
    const float* W3 = (const float*)d_in[8];
    const float* b3 = (const float*)d_in[9];
    const float* W4 = (const float*)d_in[10];
    const float* b4 = (const float*)d_in[11];

    int N = in_sizes[0] / DD;
    int M = in_sizes[1];
    int B = out_size / TT;
    float* out = (float*)d_out;

    char* ws = (char*)d_ws;
    size_t o = 0;
    auto alloc = [&](size_t bytes) -> char* {
        char* p = ws + o;
        o = (o + bytes + 255) & ~(size_t)255;
        return p;
    };
    float*  uexp = (float*)alloc((size_t)(N + 1) * 4);
    __bf16* W3f  = (__bf16*)alloc(32 * 512 * 2);
    __bf16* W4f  = (__bf16*)alloc(4 * 512 * 2);
    int*    segs = (int*)alloc((size_t)(B + 1) * 4);
    __bf16* ytab = (__bf16*)alloc((size_t)(N + 1) * DD * 2);

    int nSetup = (M + 255) / 256;
    int nScore = (N + 63) / 64;
    kMain<<<nSetup + nScore, 256, 0, stream>>>(bidx, segs, W1, W3, W3f, W4, W4f,
                                               feat, b1, W2, b2, uexp, ytab,
                                               M, B, N, nSetup);
    int ntiles = (B + 15) / 16;
    kPoolPred<<<ntiles, 512, 0, stream>>>(ytab, fidx, uexp, segs, W3f, W4f,
                                          b3, b4, out, B, N, M);
}